// Round 14
// baseline (381.757 us; speedup 1.0000x reference)
//
#include <hip/hip_runtime.h>
#include <hip/hip_bf16.h>

typedef __hip_bfloat16 bf16;
typedef __attribute__((ext_vector_type(8))) short short8;
typedef __attribute__((ext_vector_type(4))) float f32x4;
typedef __attribute__((ext_vector_type(4))) unsigned short us4;
#define DEV __device__ __forceinline__

static constexpr int T_ = 8, NC = 512, NT = 512, D_ = 256, H_ = 8, NBF = 1419;
static constexpr int FT32 = 46;             // 46 f-tiles of 32 (padded 1472)
static constexpr float EPS_ = 1e-4f;
static constexpr float DN = 0.25f;          // D^-0.25
static constexpr float DIAG_SC = 0.03125f;  // 0.5 * DN^2

DEV float bf2f(unsigned short u) { return __uint_as_float(((unsigned)u) << 16); }
DEV float tofloat(bf16 x) { return __bfloat162float(x); }
DEV unsigned short f2bu(float x) { bf16 h = __float2bfloat16(x); return *(unsigned short*)&h; }

DEV float ldx(const void* p, long i, int isb) {
  if (isb) return bf2f(((const unsigned short*)p)[i]);
  return ((const float*)p)[i];
}
DEV void stx(void* p, long i, float v, int isb) {
  if (isb) ((bf16*)p)[i] = __float2bfloat16(v);
  else     ((float*)p)[i] = v;
}

// async global->LDS 16B (wave-uniform LDS base + lane*16; global addr per-lane)
DEV void async_copy16(const void* g, void* lds) {
  __builtin_amdgcn_global_load_lds(
      (const __attribute__((address_space(1))) unsigned int*)g,
      (__attribute__((address_space(3))) unsigned int*)lds, 16, 0, 0);
}

// dtype probe logic, deterministic on a fixed 16KB sample of x (1=bf16, 0=fp32)
DEV int probe_dtype_block(const void* x, int t, int* badS) {
  if (t == 0) *badS = 0;
  __syncthreads();
  int mybad = 0;
  for (int j = 0; j < 16; j++) {
    long i = 2L * (t + 256L * j);
    unsigned short u = ((const unsigned short*)x)[i];
    int e = (u >> 7) & 0xff, mant = u & 0x7f;
    bool b = (e == 0xff) || (e >= 141) || (e <= 93 && !(e == 0 && mant == 0));
    mybad += b ? 1 : 0;
  }
  atomicAdd(badS, mybad);
  __syncthreads();
  return (*badS > 1024) ? 0 : 1;
}

// ------------------------------------------------------------------
// prep_all: merged prep, now also computes the dtype flag inline in
// every block (identical deterministic result; one block stores it for
// downstream kernels) — deletes the detect_dtype dispatch. Grid (64,8,32):
//  z 0..28 : weight pre-transpose W[k][n]->WT[n][k] bf16 (Wo folds the
//            merged-k permutation).
//  z == 29 : conv_proj — 3 f-rows per block (block (0,0,29) writes dtFlag).
//  z == 30 : xcB bf16 convert + zero of dgk/dgq/Sv atomic region.
//  z == 31 : xtB bf16 convert.
// ------------------------------------------------------------------
__global__ __launch_bounds__(256)
void prep_all(const void* __restrict__ Wk, const void* __restrict__ Wv,
              const void* __restrict__ Wq, const void* __restrict__ Wo,
              const void* __restrict__ W1, const void* __restrict__ W2,
              const void* __restrict__ W3, const void* __restrict__ Wmu,
              const void* __restrict__ proj, const void* __restrict__ x_ctx,
              const void* __restrict__ x_tgt,
              bf16* __restrict__ WkT, bf16* __restrict__ WvT,
              bf16* __restrict__ WqT, bf16* __restrict__ WoT,
              bf16* __restrict__ W1T, bf16* __restrict__ W2T,
              bf16* __restrict__ W3T, bf16* __restrict__ WmuT,
              bf16* __restrict__ projB, bf16* __restrict__ xcB,
              bf16* __restrict__ xtB,
              float* __restrict__ zbase, int* __restrict__ dtFlag)
{
  __shared__ float tile[32][33];
  __shared__ int badS;
  const int kt = blockIdx.x, nt = blockIdx.y, z = blockIdx.z, t = threadIdx.x;
  const int fl = probe_dtype_block(x_ctx, t, &badS);

  if (z == 29) {              // conv_proj (+ dtFlag store from one block)
    if (kt == 0 && nt == 0 && t == 0) *dtFlag = fl;
    int b = nt * 64 + kt;
#pragma unroll
    for (int r = 0; r < 3; r++) {
      int f = b * 3 + r;
      if (f < FT32 * 32) {
        float v = (f < NBF) ? ldx(proj, (long)f * 256 + t, fl) : 0.f;
        projB[(long)f * 256 + t] = __float2bfloat16(v);
      }
    }
    return;
  }
  if (z == 30) {              // xcB convert + atomic-region zero
    int b = nt * 64 + kt;
#pragma unroll
    for (int j = 0; j < 8; j++) {
      long i = (long)b * 2048 + j * 256 + t;
      xcB[i] = __float2bfloat16(ldx(x_ctx, i, fl));
    }
    if (b < 320) zbase[b * 256 + t] = 0.f;
    return;
  }
  if (z == 31) {              // xtB convert
    int b = nt * 64 + kt;
#pragma unroll
    for (int j = 0; j < 8; j++) {
      long i = (long)b * 2048 + j * 256 + t;
      xtB[i] = __float2bfloat16(ldx(x_tgt, i, fl));
    }
    return;
  }

  const void* in; bf16* out; int K; int perm = 0; long off = 0;
  if (z < 8)        { in = Wk;  out = WkT;  K = 256; off = (long)z * 65536; }
  else if (z < 16)  { in = Wv;  out = WvT;  K = 256; off = (long)(z - 8) * 65536; }
  else if (z < 24)  { in = Wq;  out = WqT;  K = 256; off = (long)(z - 16) * 65536; }
  else if (z == 24) { in = Wo;  out = WoT;  K = 2048; perm = 1; }
  else if (z == 25) { in = W1;  out = W1T;  K = 256; }
  else if (z == 26) { in = W2;  out = W2T;  K = 256; }
  else if (z == 27) { in = W3;  out = W3T;  K = 256; }
  else              { in = Wmu; out = WmuT; K = 256; }
  if (K == 256 && kt >= 8) return;
  const int k0 = kt * 32, n0 = nt * 32;
  const int row = t >> 3, cb = (t & 7) * 4;
  {
    int kk = k0 + row;
    int krow = perm ? (((kk & 255) << 3) | (kk >> 8)) : kk;
#pragma unroll
    for (int j = 0; j < 4; j++)
      tile[row][cb + j] = ldx(in, off + (long)krow * 256 + n0 + cb + j, fl);
  }
  __syncthreads();
  us4 o;
#pragma unroll
  for (int j = 0; j < 4; j++) o[j] = f2bu(tile[cb + j][row]);
  *(us4*)(out + off + (long)(n0 + row) * K + k0 + cb) = o;
}

// ------------------------------------------------------------------
// gemm_kv: k-projection and v-projection MERGED into one dispatch
// (grid (4,8,128): z<64 kproj xcB.WkT->kB + fused diag; z>=64 vproj
// cf.WvT->vQ tiled + fused Sv). Independent work co-schedules; one
// launch gap deleted. Body = the proven v2 64x64 K-step-64 loop.
// ------------------------------------------------------------------
__global__ __launch_bounds__(256)
void gemm_kv(const bf16* __restrict__ xcB, const bf16* __restrict__ cf,
             const bf16* __restrict__ WkT, const bf16* __restrict__ WvT,
             const void* __restrict__ bk, const void* __restrict__ bv,
             bf16* __restrict__ kB, bf16* __restrict__ vQ,
             float* __restrict__ dgk, float* __restrict__ Sv,
             const int* __restrict__ dtFlag)
{
  __shared__ alignas(16) bf16 As[2][64 * 64];
  __shared__ alignas(16) bf16 Bs[2][64 * 64];
  const int fl = *dtFlag;
  const int t = threadIdx.x;
  const int z = blockIdx.z;
  const int isV = z >> 6;
  const int bz = z & 63;
  const bf16* A = isV ? cf : xcB;
  const bf16* BT = isV ? WvT : WkT;
  const void* bias = isV ? bv : bk;
  bf16* C = isV ? vQ : kB;
  const int K = 256, M = 512, N = 256;
  const long aOff = (long)(bz >> 3) * 131072;
  const long bOff = (long)(bz & 7) * 65536;
  const long biasOff = (long)(bz & 7) * 256;
  const long cOff = (long)bz * 131072;
  const int m0 = blockIdx.y * 64, n0 = blockIdx.x * 64;
  const int w = t >> 6, l = t & 63, quad = l >> 4, ln = l & 15;
  const bf16* Ab = A + aOff + (long)m0 * K;
  const bf16* Bb = BT + bOff + (long)n0 * K;
  const int srow = l >> 3;
  const int scc = (l & 7) ^ srow;
  f32x4 acc[4] = {};

  auto stage = [&](int buf, int k0) {
#pragma unroll
    for (int j = 0; j < 2; j++) {
      const int rbase = 32 * j + 8 * w;
      const int row = rbase + srow;
      async_copy16(Ab + (long)row * K + k0 + scc * 8, &As[buf][rbase * 64]);
      async_copy16(Bb + (long)row * K + k0 + scc * 8, &Bs[buf][rbase * 64]);
    }
  };

  stage(0, 0);
  __syncthreads();

  int cur = 0;
  for (int k0 = 0; k0 < K; k0 += 64) {
    if (k0 + 64 < K) stage(cur ^ 1, k0 + 64);
    const bf16* Ac = &As[cur][0];
    const bf16* Bc = &Bs[cur][0];
    const int arow = 16 * w + ln;
#pragma unroll
    for (int ks = 0; ks < 2; ks++) {
      short8 a = *(const short8*)(Ac + arow * 64 + (((ks * 4 + quad) ^ (arow & 7)) << 3));
#pragma unroll
      for (int i = 0; i < 4; i++) {
        const int brow = 16 * i + ln;
        short8 b = *(const short8*)(Bc + brow * 64 + (((ks * 4 + quad) ^ (brow & 7)) << 3));
        acc[i] = __builtin_amdgcn_mfma_f32_16x16x32_bf16(a, b, acc[i], 0, 0, 0);
      }
    }
    asm volatile("s_waitcnt vmcnt(0)" ::: "memory");
    __builtin_amdgcn_s_barrier();
    __builtin_amdgcn_sched_barrier(0);
    cur ^= 1;
  }

  if (isV) {
    // vproj epilogue: MFMA-tiled store + fused column-sum Sv
    const int mm = m0 + 16 * w + quad * 4;
    const int tileI = mm >> 5, off = mm & 31;
#pragma unroll
    for (int i = 0; i < 4; i++) {
      int n = n0 + 16 * i + ln;
      us4 cv;
      float colsum = 0.f;
#pragma unroll
      for (int r = 0; r < 4; r++) {
        float c = acc[i][r] + ldx(bias, biasOff + n, fl);
        colsum += c;
        cv[r] = f2bu(c);
      }
      *(us4*)(C + cOff + ((long)tileI * N + n) * 32 + off) = cv;
      colsum += __shfl_xor(colsum, 16);
      colsum += __shfl_xor(colsum, 32);
      if (quad == 0) atomicAdd(&Sv[(long)bz * N + n], colsum);
    }
  } else {
    // kproj epilogue: natural store + fused diag
    float s2[4] = {0.f, 0.f, 0.f, 0.f};
#pragma unroll
    for (int i = 0; i < 4; i++) {
#pragma unroll
      for (int r = 0; r < 4; r++) {
        int m = m0 + 16 * w + quad * 4 + r;
        int n = n0 + 16 * i + ln;
        float c = acc[i][r] + ldx(bias, biasOff + n, fl);
        s2[r] += c * c;
        C[cOff + (long)m * N + n] = __float2bfloat16(c);
      }
    }
#pragma unroll
    for (int r = 0; r < 4; r++) {
      float s = s2[r];
      s += __shfl_xor(s, 1); s += __shfl_xor(s, 2);
      s += __shfl_xor(s, 4); s += __shfl_xor(s, 8);
      if (ln == 0)
        atomicAdd(&dgk[(long)bz * M + m0 + 16 * w + quad * 4 + r], DIAG_SC * s);
    }
  }
}

// ------------------------------------------------------------------
// BM=32 GEMM v3 (round-13 proven): triple-buffered, distance-2,
// counted vmcnt(3), tail vmcnt(0). Optional label fold. Generic K.
// ------------------------------------------------------------------
__global__ __launch_bounds__(256)
void gemm_mfma32v2(const bf16* __restrict__ A, const bf16* __restrict__ BT,
                   const void* __restrict__ bias,
                   void* __restrict__ C, int cMode, int epi,
                   const int* __restrict__ dtFlag, int M, int N, int K,
                   const void* __restrict__ labp, const void* __restrict__ labW)
{
  __shared__ alignas(16) bf16 As[3][32 * 64];
  __shared__ alignas(16) bf16 Bs[3][64 * 64];
  const int fl = *dtFlag;
  const int cB = (cMode == 2) ? fl : cMode;
  const int t = threadIdx.x;
  const int m0 = blockIdx.y * 32, n0 = blockIdx.x * 64;
  const int w = t >> 6, l = t & 63, quad = l >> 4, ln = l & 15;
  const int mi = w & 1, nh = w >> 1;
  const bf16* Ab = A + (long)m0 * K;
  const bf16* Bb = BT + (long)n0 * K;
  const int srow = l >> 3;
  const int scc = (l & 7) ^ srow;
  const int niter = K >> 6;
  f32x4 acc[2] = {};

  auto stage = [&](int buf, int k0) {
    async_copy16(Ab + (long)(8 * w + srow) * K + k0 + scc * 8, &As[buf][(8 * w) * 64]);
#pragma unroll
    for (int j = 0; j < 2; j++) {
      const int rbase = 32 * j + 8 * w;
      async_copy16(Bb + (long)(rbase + srow) * K + k0 + scc * 8, &Bs[buf][rbase * 64]);
    }
  };

  stage(0, 0);
  if (niter > 1) stage(1, 64);
  __syncthreads();   // full drain: buffers 0,1 ready

  int cur = 0;
  for (int it = 0; it < niter; ++it) {
    if (it + 2 < niter) {
      int nb = cur + 2; if (nb >= 3) nb -= 3;
      stage(nb, (it + 2) * 64);
    }
    __builtin_amdgcn_sched_barrier(0);
    const bf16* Ac = &As[cur][0];
    const bf16* Bc = &Bs[cur][0];
    const int arow = 16 * mi + ln;
#pragma unroll
    for (int ks = 0; ks < 2; ks++) {
      short8 a = *(const short8*)(Ac + arow * 64 + (((ks * 4 + quad) ^ (arow & 7)) << 3));
#pragma unroll
      for (int i = 0; i < 2; i++) {
        const int brow = 16 * (2 * nh + i) + ln;
        short8 b = *(const short8*)(Bc + brow * 64 + (((ks * 4 + quad) ^ (brow & 7)) << 3));
        acc[i] = __builtin_amdgcn_mfma_f32_16x16x32_bf16(a, b, acc[i], 0, 0, 0);
      }
    }
    if (it + 2 < niter) {
      asm volatile("s_waitcnt vmcnt(3)" ::: "memory");
    } else {
      asm volatile("s_waitcnt vmcnt(0)" ::: "memory");
    }
    __builtin_amdgcn_s_barrier();
    __builtin_amdgcn_sched_barrier(0);
    cur = (cur == 2) ? 0 : cur + 1;
  }

#pragma unroll
  for (int i = 0; i < 2; i++) {
#pragma unroll
    for (int r = 0; r < 4; r++) {
      int m = m0 + 16 * mi + quad * 4 + r;
      int n = n0 + 16 * (2 * nh + i) + ln;
      float c = acc[i][r];
      if (epi >= 1) c += ldx(bias, n, fl);
      if (labp) {
#pragma unroll
        for (int j = 0; j < 3; j++)
          c += ldx(labp, (long)m * 3 + j, fl) * ldx(labW, (long)(256 + j) * 256 + n, fl);
      }
      if (epi == 2) c = fmaxf(c, 0.f);
      stx(C, (long)m * N + n, c, cB);
    }
  }
}

// ------------------------------------------------------------------
// Key-side fused v10 (round-13 proven, 90.7us): v5 staging (kS[3],
// distance-2, one barrier/iter, counted vmcnt(4) with tail drain) +
// de-atomized csRp/ktotp partial-store epilogue.
// ------------------------------------------------------------------
__global__ __launch_bounds__(256)
void key_fused_mfma(const bf16* __restrict__ k, const bf16* __restrict__ vQ,
                    const bf16* __restrict__ projB, const float* __restrict__ diagk,
                    float* __restrict__ ksumE, bf16* __restrict__ ctxQ,
                    float* __restrict__ mpart, float* __restrict__ csRp,
                    float* __restrict__ ktotp)
{
  __shared__ alignas(16) bf16 kS[3][32 * 256];
  __shared__ alignas(16) bf16 pS[2][64 * 40];
  __shared__ float wredM[4];
  __shared__ float wredK[4];

  const int bz = blockIdx.x, ft = blockIdx.y, f0 = ft * 64;
  const int t = threadIdx.x;
  const int w = t >> 6, l = t & 63, quad = l >> 4, ln = l & 15;
  const int fmine = f0 + 16 * w + ln;
  const bool fv = fmine < NBF;

  const bf16* kb = k + (long)bz * NC * 256;
  const bf16* vqb = vQ + (long)bz * 16 * 256 * 32;
  const float* db = diagk + bz * NC;

  auto stage = [&](int buf, int n0) {
#pragma unroll
    for (int j = 0; j < 4; j++) {
      int row = w * 8 + j * 2 + (l >> 5);
      int cc = (l & 31) ^ ((2 * j + (l >> 5)) & 7);   // = (l&31) ^ (row&7)
      async_copy16(kb + (long)(n0 + row) * 256 + cc * 8,
                   &kS[buf][w * 2048 + j * 512]);
    }
  };
  stage(0, 0);
  stage(1, 32);

  short8 pf[8];
  {
    const bf16* prow = projB + (long)fmine * 256;
#pragma unroll
    for (int kc = 0; kc < 8; kc++)
      pf[kc] = *(const short8*)(prow + kc * 32 + quad * 8);
  }

  f32x4 acc[4][4] = {};
  float ksumP = 0.f, mP = -1e30f;

  __syncthreads();   // full drain once: kS[0], kS[1] + pf ready

  int cur = 0;       // buffer holding tile `it`
  for (int it = 0; it < 16; it++) {
    const int n0 = it * 32;
    short8 bfr[4];
#pragma unroll
    for (int ei = 0; ei < 4; ei++) {
      int e = 64 * w + 16 * ei + ln;
      bfr[ei] = *(const short8*)(vqb + ((long)it * 256 + e) * 32 + quad * 8);
    }
    f32x4 dv0 = *(const f32x4*)(db + n0 + quad * 4);
    f32x4 dv1 = *(const f32x4*)(db + n0 + 16 + quad * 4);
    __builtin_amdgcn_sched_barrier(0);
    if (it + 2 < 16) {
      int nb = cur + 2; if (nb >= 3) nb -= 3;
      stage(nb, n0 + 64);
    }
    __builtin_amdgcn_sched_barrier(0);

    const bf16* kcur = &kS[cur][0];
    f32x4 dd[2][2] = {};
    __builtin_amdgcn_s_setprio(1);
#pragma unroll
    for (int kc = 0; kc < 8; kc++) {
      const int hf = kc & 1;
#pragma unroll
      for (int mi = 0; mi < 2; mi++) {
        short8 a = *(const short8*)(kcur + (16 * mi + ln) * 256 +
                                    (((kc * 4 + quad) ^ (ln & 7)) << 3));
        dd[mi][hf] = __builtin_amdgcn_mfma_f32_16x16x32_bf16(a, pf[kc], dd[mi][hf], 0, 0, 0);
      }
    }
    __builtin_amdgcn_s_setprio(0);
    bf16* pcur = &pS[it & 1][0];
#pragma unroll
    for (int mi = 0; mi < 2; mi++) {
      us4 ev;
      f32x4 dvv = mi ? dv1 : dv0;
#pragma unroll
      for (int r = 0; r < 4; r++) {
        float sc = DN * (dd[mi][0][r] + dd[mi][1][r]);
        float E = fv ? __expf(fminf(sc - dvv[r], 80.f)) : 0.f;
        unsigned short u = f2bu(E);
        ksumP += bf2f(u);
        if (fv) mP = fmaxf(mP, sc);
        ev[r] = u;
      }
      *(us4*)(pcur + (16 * w + ln) * 40 + 16 * mi + quad * 4) = ev;
    }
    if (it + 2 < 16) {
      asm volatile("s_waitcnt vmcnt(4) lgkmcnt(0)" ::: "memory");
    } else {
      asm volatile("s_waitcnt vmcnt(0) lgkmcnt(0)" ::: "memory");
    }
    __builtin_amdgcn_s_barrier();
    __builtin_amdgcn_sched_barrier(0);

    __builtin_amdgcn_s_setprio(1);
#pragma unroll
    for (int fh = 0; fh < 4; fh++) {
      short8 a = *(const short8*)(pcur + (16 * fh + ln) * 40 + quad * 8);
#pragma unroll
      for (int ei = 0; ei < 4; ei++)
        acc[fh][ei] = __builtin_amdgcn_mfma_f32_16x16x32_bf16(a, bfr[ei], acc[fh][ei], 0, 0, 0);
    }
    __builtin_amdgcn_s_setprio(0);
    cur = (cur == 2) ? 0 : cur + 1;
  }
  __syncthreads();

#pragma unroll
  for (int fh = 0; fh < 4; fh++) {
    const int ft32 = 2 * ft + (fh >> 1);
    const int f32b = 16 * (fh & 1) + quad * 4;
#pragma unroll
    for (int ei = 0; ei < 4; ei++) {
      int e = 64 * w + 16 * ei + ln;
      us4 cv;
#pragma unroll
      for (int r = 0; r < 4; r++) cv[r] = f2bu(acc[fh][ei][r]);
      *(us4*)(&ctxQ[((long)(bz * FT32 + ft32) * 256 + e) * 32 + f32b]) = cv;
    }
  }

  // csRp partial: column sum over this block's 64 f-rows per e (plain store)
#pragma unroll
  for (int ei = 0; ei < 4; ei++) {
    float col = 0.f;
#pragma unroll
    for (int fh = 0; fh < 4; fh++)
#pragma unroll
      for (int r = 0; r < 4; r++) col += acc[fh][ei][r];
    col += __shfl_xor(col, 16);
    col += __shfl_xor(col, 32);
    if (quad == 0)
      csRp[((long)bz * 23 + ft) * 256 + 64 * w + 16 * ei + ln] = col;
  }

  float s = ksumP;
  s += __shfl_xor(s, 16); s += __shfl_xor(s, 32);
  if (quad == 0 && fv) ksumE[(long)bz * NBF + fmine] = s;
  float s2 = s;
  s2 += __shfl_xor(s2, 1); s2 += __shfl_xor(s2, 2);
  s2 += __shfl_xor(s2, 4); s2 += __shfl_xor(s2, 8);
  if (l == 0) wredK[w] = s2;

  float m = mP;
#pragma unroll
  for (int off = 1; off < 64; off <<= 1) m = fmaxf(m, __shfl_xor(m, off));
  if (l == 0) wredM[w] = m;
  __syncthreads();
  if (t == 0) {
    mpart[bz * 23 + ft] = fmaxf(fmaxf(wredM[0], wredM[1]), fmaxf(wredM[2], wredM[3]));
    ktotp[bz * 23 + ft] = wredK[0] + wredK[1] + wredK[2] + wredK[3];
  }
}

// ------------------------------------------------------------------
// Query-side fused v10 (round-13 proven): q-proj prologue + folded
// finalize (csRp/ktotp/mpart partial reductions) + folded normalize.
// ------------------------------------------------------------------
__global__ __launch_bounds__(256)
void q_fused_mfma(const bf16* __restrict__ xtB, const bf16* __restrict__ WqT,
                  const void* __restrict__ bq, const bf16* __restrict__ projB,
                  const bf16* __restrict__ ctxQ,
                  const float* __restrict__ ksum, const float* __restrict__ Sv,
                  const float* __restrict__ csRp, const float* __restrict__ ktotp,
                  const float* __restrict__ mpart, const int* __restrict__ dtFlag,
                  bf16* __restrict__ merged)
{
  __shared__ alignas(16) bf16 projS[3][32 * 256];
  __shared__ alignas(16) bf16 eS[2][64 * 40];
  __shared__ float dS[64];
  __shared__ float svS[256];
  __shared__ float crS[256];
  __shared__ float sS[64];
  __shared__ float mS[64];
  __shared__ float seS[64];

  const int fl = *dtFlag;
  const int bz = blockIdx.x, nt = blockIdx.y, t = threadIdx.x;
  const int w = t >> 6, l = t & 63, quad = l >> 4, ln = l & 15;
  const int tq = bz / H_, hh = bz % H_;
  const bf16* cqb = ctxQ + (long)bz * FT32 * 256 * 32;
  const int srow = l >> 3, scc = (l & 7) ^ srow;

  // folded finalize_red: csR/ktot/mk from partials
  float mkv = -1e30f, ktv = 0.f;
  {
    float s = 0.f;
    for (int f2 = 0; f2 < 23; f2++) {
      s += csRp[((long)bz * 23 + f2) * 256 + t];
      mkv = fmaxf(mkv, mpart[bz * 23 + f2]);
      ktv += ktotp[bz * 23 + f2];
    }
    crS[t] = s;
  }
  const float emk = __expf(-mkv);
  const float ktotv = ktv;

  // ---- fused q-projection prologue (uses projS as scratch) ----
  bf16* scr = &projS[0][0];
  bf16* Asq = scr;             // [64][64] swizzled
  bf16* Bsq = scr + 4096;      // [256][64] swizzled
  const bf16* xq = xtB + ((long)tq * NT + nt * 64) * 256;
  const bf16* wq = WqT + (long)hh * 65536;
  f32x4 qacc[16] = {};

  for (int k0 = 0; k0 < 256; k0 += 64) {
#pragma unroll
    for (int j = 0; j < 2; j++) {
      const int rbase = 16 * w + 8 * j;
      async_copy16(xq + (long)(rbase + srow) * 256 + k0 + scc * 8, Asq + rbase * 64);
    }
#pragma unroll
    for (int j = 0; j < 8; j++) {
      const int rbase = 64 * w + 8 * j;
      async_copy16(wq + (long)(rbase + srow) * 256 + k0 + scc * 8, Bsq + rbase * 64);
    }
    asm volatile("s_waitcnt vmcnt(0)" ::: "memory");
    __builtin_amdgcn_s_barrier();
    __builtin_amdgcn_sched_barrier(0);
    const int arow = 16 * w + ln;
#pragma unroll
    for (int ks = 0; ks < 2; ks++) {
      short8 a = *(const short8*)(Asq + arow * 64 + (((ks * 4 + quad) ^ (arow & 7)) << 3));
#pragma unroll
      for (int g = 0; g < 16; g++) {
        const int brow = 16 * g + ln;
        short8 b = *(const short8*)(Bsq + brow * 64 + (((ks * 4 + quad) ^ (brow & 7)) << 3));
        qacc[g] = __builtin_amdgcn_mfma_f32_16x16x32_bf16(a, b, qacc[g], 0, 0, 0);
      }
    }
    __syncthreads();   // protect single-buffered restage / final scratch reuse
  }
  // bias + diag + bf16 q-tile into scr (stride 264)
  {
    float sum2[4] = {0.f, 0.f, 0.f, 0.f};
#pragma unroll
    for (int g = 0; g < 16; g++) {
      float bias = ldx(bq, (long)hh * 256 + 16 * g + ln, fl);
#pragma unroll
      for (int r = 0; r < 4; r++) {
        float v = qacc[g][r] + bias;
        sum2[r] += v * v;
        scr[(16 * w + quad * 4 + r) * 264 + 16 * g + ln] = __float2bfloat16(v);
      }
    }
#pragma unroll
    for (int r = 0; r < 4; r++) {
      float s = sum2[r];
      s += __shfl_xor(s, 1); s += __shfl_xor(s, 2);
      s += __shfl_xor(s, 4); s += __shfl_xor(s, 8);
      if (ln == 0) dS[16 * w + quad * 4 + r] = DIAG_SC * s;
    }
  }
  asm volatile("s_waitcnt lgkmcnt(0)" ::: "memory");
  __builtin_amdgcn_sched_barrier(0);
  // qf fragments (rows 16w+ln: written by THIS wave -> no barrier needed)
  short8 qf[8];
#pragma unroll
  for (int kc = 0; kc < 8; kc++)
    qf[kc] = *(const short8*)(scr + (16 * w + ln) * 264 + kc * 32 + quad * 8);
  __syncthreads();   // all reads done before stage_proj DMA overwrites scr

  auto stage_proj = [&](int buf, int f0n) {
#pragma unroll
    for (int j = 0; j < 4; j++) {
      int row = 8 * w + 2 * j + (l >> 5);
      int cc = (l & 31) ^ (row & 7);
      async_copy16(projB + (long)(f0n + row) * 256 + cc * 8,
                   &projS[buf][(8 * w + 2 * j) * 256]);
    }
  };
  stage_proj(0, 0);
  stage_proj(1, 32);
  svS[t] = Sv[bz * 256 + t];

  f32x4 acc[4][4] = {};           // [mh][ei]: rows 16mh+quad*4+r, e=16(4w+ei)+ln
  float sPart[4] = {0.f, 0.f, 0.f, 0.f};   // stR partial (rows 16w+quad*4+r)
  float sEp[4] = {0.f, 0.f, 0.f, 0.f};     // sE partial
  float mPart[4] = {0.f, 0.f, 0.f, 0.f};
  __syncthreads();   // full drain: projS[0..1] + LDS scalars ready

  int cur = 0;       // buffer holding tile `ft`
  for (int ft = 0; ft < FT32; ft++) {
    const int f0 = ft * 32;
    const bf16* pcur = &projS[cur][0];
    short8 cfr[4];
#pragma unroll
    for (int i = 0; i < 4; i++) {
      int e = 16 * (4 * w + i) + ln;
      cfr[i] = *(const short8*)(cqb + ((long)ft * 256 + e) * 32 + quad * 8);
    }
    const float kv0 = (f0 + ln < NBF) ? ksum[(long)bz * NBF + f0 + ln] : 0.f;
    const float kv1 = (f0 + 16 + ln < NBF) ? ksum[(long)bz * NBF + f0 + 16 + ln] : 0.f;
    __builtin_amdgcn_sched_barrier(0);
    if (ft + 2 < FT32) {
      int nb = cur + 2; if (nb >= 3) nb -= 3;
      stage_proj(nb, f0 + 64);
    }
    __builtin_amdgcn_sched_barrier(0);

    // Phase A: wave w owns rows 16w..16w+15, both f-halves
    f32x4 dd0 = {}, dd1 = {};
    __builtin_amdgcn_s_setprio(1);
#pragma unroll
    for (int kc = 0; kc < 8; kc++) {
      const int co = ((kc * 4 + quad) ^ (ln & 7)) << 3;
      short8 b0 = *(const short8*)(pcur + ln * 256 + co);
      dd0 = __builtin_amdgcn_mfma_f32_16x16x32_bf16(qf[kc], b0, dd0, 0, 0, 0);
      short8 b1 = *(const short8*)(pcur + (16 + ln) * 256 + co);
      dd1 = __builtin_amdgcn_mfma_f32_16x16x32_bf16(qf[kc], b1, dd1, 0, 0, 0);
    }
    __builtin_amdgcn_s_setprio(0);
    const bool fv0 = (f0 + ln) < NBF;
    const bool fv1 = (f0 + 16 + ln) < NBF;
    bf16* ecur = &eS[ft & 1][0];
#pragma unroll
    for (int r = 0; r < 4; r++) {
      float E0 = fv0 ? __expf(fminf(DN * dd0[r], 80.f)) : 0.f;
      float E1 = fv1 ? __expf(fminf(DN * dd1[r], 80.f)) : 0.f;
      bf16 h0 = __float2bfloat16(E0), h1v = __float2bfloat16(E1);
      float e0 = tofloat(h0), e1 = tofloat(h1v);
      ecur[(16 * w + quad * 4 + r) * 40 + ln] = h0;
      ecur[(16 * w + quad * 4 + r) * 40 + 16 + ln] = h1v;
      sPart[r] += e0 * kv0 + e1 * kv1;
      sEp[r] += e0 + e1;
      mPart[r] = fmaxf(mPart[r], fmaxf(e0, e1));
    }
    if (ft + 2 < FT32) {
      asm volatile("s_waitcnt vmcnt(4) lgkmcnt(0)" ::: "memory");
    } else {
      asm volatile("s_waitcnt vmcnt(0) lgkmcnt(0)" ::: "memory");
    }
    __builtin_amdgcn_s_barrier();
    __builtin_amdgcn_sched_barrier(0);

    // Phase B: all 4 m-halves, 4 e-tiles each (cfr reused)
    __builtin_amdgcn_s_setprio(1);
#pragma unroll
    for (int mh = 0; mh < 4; mh++) {
      short8 a = *(const short8*)(ecur + (16 * mh + ln) * 40 + quad * 8);
#pragma unroll
      for (int i = 0; i < 4; i++)
        acc[mh][i] = __builtin_amdgcn_mfma_f32_16x16x32_bf16(a, cfr[i], acc[mh][i], 0, 0, 0);
    }
    __builtin_amdgcn_s_setprio(0);
    cur = (cur == 2) ? 0 : cur + 1;
  }
  __syncthreads();

  // wave-private row stats: reduce over 16 lanes
#pragma unroll
  for (int r = 0; r < 4; r++) {
    float s = sPart[r], m = mPart[r], se = sEp[r];
#pragma unroll
    for (int off = 1; off < 16; off <<= 1) {
      s += __shfl_xor(s, off);
      m = fmaxf(m, __shfl_xor(m, off));
      se += __shfl_xor(se, off);
    }
    if (ln == 0) {
      sS[16 * w + quad * 4 + r] = s;
      mS[16 * w + quad * 4 + r] = m;
      seS[16 * w + quad * 4 + r] = se;
    }
  }
  __syncthreads();

#pragma unroll
  for (int mh = 0; mh < 4; mh++) {
#pragma unroll
    for (int r = 0; r < 4; r++) {
      int row = 16 * mh + quad * 4 + r;
      float st = sS[row];
      float se = seS[row];
      float mt = fmaxf(mS[row], 1e-30f);
      float c = __expf(-dS[row]) / mt;
      float A = c * se + (float)NBF * EPS_;
      float den = emk * (c * st + EPS_ * ktotv) + (float)NC * EPS_ * A;
      float inv = 1.f / den;
#pragma unroll
      for (int i = 0; i < 4; i++) {
        int e = 16 * (4 * w + i) + ln;
        float val = (emk * (c * acc[mh][i][r] + EPS_ * crS[e]) + EPS_ * svS[e] * A) * inv;
        merged[((long)tq * NT + nt * 64 + row) * 2048 + hh * 256 + e] =
            __float2bfloat16(val);
      }
    }
  }
}

// ------------------------------------------------------------------
extern "C" void kernel_launch(void* const* d_in, const int* in_sizes, int n_in,
                              void* d_out, int out_size, void* d_ws, size_t ws_size,
                              hipStream_t stream)
{
  const void* x_ctx = d_in[0];
  const void* label = d_in[1];
  const void* x_tgt = d_in[2];
  const void* W1 = d_in[3];
  const void* b1 = d_in[4];
  const void* W2 = d_in[5];
  const void* b2 = d_in[6];
  const void* W3 = d_in[7];
  const void* b3 = d_in[8];
  const void* Wk = d_in[9];
  const void* bk = d_in[10];
  const void* Wv = d_in[11];
  const void* bv = d_in[12];
  const void* Wq = d_in[13];
  const void* bq = d_in[14];
  const void* Wo = d_in[15];
  const void* bo = d_in[16];
  const void* Wmu = d_in[17];
  const void* bmu = d_in[18];
  const void* proj = d_in[19];

  // Arena (floats), peak ~93 MB. Overlays:
  //  xcB @ F2+1572864 (dead before ctxQ written by key_fused)
  //  rep @ F0+1048576 (written by Wo GEMM after q_fused; kB dead then)
  //  xtB: dedicated slot (written in prep, read in q_fused)
  float* W = (float*)d_ws;
  const long F0 = 0, F1 = 4194304, F2 = 8388608;
  const long CTXQ_F = (long)64 * FT32 * 256 * 32 / 2;
  const long F3 = F2 + CTXQ_F;
  bf16* kB = (bf16*)(W + F0);
  bf16* rep = (bf16*)(W + F0 + 1048576);
  bf16* vQ = (bf16*)(W + F1);
  bf16* merged = (bf16*)(W + F1);
  bf16* h1 = (bf16*)(W + F2);
  bf16* h2 = (bf16*)(W + F2 + 524288);
  bf16* cf = (bf16*)(W + F2 + 1048576);
  bf16* xcB = (bf16*)(W + F2 + 1572864);
  bf16* ctxQ = (bf16*)(W + F2);
  long o = F3;
  auto alloc = [&](long n) { float* p = W + o; o += n; return p; };
  float* zbase = W + o;
  float* dgk = alloc(32768);
  float* dgq = alloc(32768);            // kept for zero-region layout
  float* Sv = alloc(64 * 256);          // end of zeroed region (320 blocks)
  float* csR = alloc(64 * 256);         // unused (finalize folded)
  float* ktotR = alloc(64);             // unused
  alloc(192);
  float* ksumE = alloc((long)64 * NBF);
  float* mpart = alloc(64 * 23);
  float* mk = alloc(64);                // unused
  int* dtFlag = (int*)alloc(64);
  float* csRp = alloc((long)64 * 23 * 256);
  float* ktotp = alloc(64 * 23);
  bf16* projB = (bf16*)alloc((long)FT32 * 32 * 256 / 2);
  bf16* xtB = (bf16*)alloc(524288);   // 1M bf16 (8x512x256)
  bf16* WkT = (bf16*)alloc(262144);   // 8 x 256 x 256 bf16
  bf16* WvT = (bf16*)alloc(262144);
  bf16* WqT = (bf16*)alloc(262144);
  bf16* WoT = (bf16*)alloc(262144);   // 256 x 2048 bf16 (perm folded)
  bf16* W1T = (bf16*)alloc(32768);    // 256 x 256 bf16
  bf16* W2T = (bf16*)alloc(32768);
  bf16* W3T = (bf16*)alloc(32768);
  bf16* WmuT = (bf16*)alloc(32768);
  (void)ws_size; (void)in_sizes; (void)n_in; (void)out_size;
  (void)dgq; (void)csR; (void)ktotR; (void)mk;

  const dim3 B(256);
  // merged prep (computes dtype flag inline; no detect dispatch)
  prep_all<<<dim3(64, 8, 32), B, 0, stream>>>(
      Wk, Wv, Wq, Wo, W1, W2, W3, Wmu, proj, x_ctx, x_tgt,
      WkT, WvT, WqT, WoT, W1T, W2T, W3T, WmuT, projB, xcB, xtB, zbase, dtFlag);
  // 1. task-encoder MLP (BM=32 counted-wait gemm; layer 1 folds label+relu)
  gemm_mfma32v2<<<dim3(4, 128), B, 0, stream>>>(
      xcB, W1T, b1, h1, 1, 2, dtFlag, 4096, 256, 256, label, W1);
  gemm_mfma32v2<<<dim3(4, 128), B, 0, stream>>>(
      h1, W2T, b2, h2, 1, 2, dtFlag, 4096, 256, 256, nullptr, nullptr);
  gemm_mfma32v2<<<dim3(4, 128), B, 0, stream>>>(
      h2, W3T, b3, cf, 1, 2, dtFlag, 4096, 256, 256, nullptr, nullptr);
  // 2. k-proj + v-proj merged (co-scheduled, one dispatch)
  gemm_kv<<<dim3(4, 8, 128), B, 0, stream>>>(
      xcB, cf, WkT, WvT, bk, bv, kB, vQ, dgk, Sv, dtFlag);
  // 3. key side (emits csRp / ktotp partials; finalize folded into q_fused)
  key_fused_mfma<<<dim3(64, 23), B, 0, stream>>>(kB, vQ, projB, dgk, ksumE, ctxQ,
                                                 mpart, csRp, ktotp);
  // 4. query side v10 (q-proj + finalize + normalize folded) -> merged
  q_fused_mfma<<<dim3(64, 8), B, 0, stream>>>(xtB, WqT, bq, projB, ctxQ, ksumE,
                                              Sv, csRp, ktotp, mpart, dtFlag, merged);
  // 5. Wo GEMM (single pass, K=2048, counted-wait) then Wmu
  gemm_mfma32v2<<<dim3(4, 128), B, 0, stream>>>(
      merged, WoT, bo, rep, 1, 1, dtFlag, 4096, 256, 2048, nullptr, nullptr);
  gemm_mfma32v2<<<dim3(4, 128), B, 0, stream>>>(
      rep, WmuT, bmu, d_out, 2, 1, dtFlag, 4096, 256, 256, nullptr, nullptr);
}

// Round 15
// 359.205 us; speedup vs baseline: 1.0628x; 1.0628x over previous
//
#include <hip/hip_runtime.h>
#include <hip/hip_bf16.h>

typedef __hip_bfloat16 bf16;
typedef __attribute__((ext_vector_type(8))) short short8;
typedef __attribute__((ext_vector_type(4))) float f32x4;
typedef __attribute__((ext_vector_type(4))) unsigned short us4;
#define DEV __device__ __forceinline__

static constexpr int T_ = 8, NC = 512, NT = 512, D_ = 256, H_ = 8, NBF = 1419;
static constexpr int FT32 = 46;             // 46 f-tiles of 32 (padded 1472)
static constexpr float EPS_ = 1e-4f;
static constexpr float DN = 0.25f;          // D^-0.25
static constexpr float DIAG_SC = 0.03125f;  // 0.5 * DN^2

DEV float bf2f(unsigned short u) { return __uint_as_float(((unsigned)u) << 16); }
DEV float tofloat(bf16 x) { return __bfloat162float(x); }
DEV unsigned short f2bu(float x) { bf16 h = __float2bfloat16(x); return *(unsigned short*)&h; }

DEV float ldx(const void* p, long i, int isb) {
  if (isb) return bf2f(((const unsigned short*)p)[i]);
  return ((const float*)p)[i];
}
DEV void stx(void* p, long i, float v, int isb) {
  if (isb) ((bf16*)p)[i] = __float2bfloat16(v);
  else     ((float*)p)[i] = v;
}

// async global->LDS 16B (wave-uniform LDS base + lane*16; global addr per-lane)
DEV void async_copy16(const void* g, void* lds) {
  __builtin_amdgcn_global_load_lds(
      (const __attribute__((address_space(1))) unsigned int*)g,
      (__attribute__((address_space(3))) unsigned int*)lds, 16, 0, 0);
}

// ------------------------------------------------------------------
// dtype probe (1 = bf16 inputs, 0 = fp32)
// ------------------------------------------------------------------
__global__ __launch_bounds__(256)
void detect_dtype(const void* __restrict__ x, int* __restrict__ flag)
{
  __shared__ int bad;
  if (threadIdx.x == 0) bad = 0;
  __syncthreads();
  int mybad = 0;
  for (int j = 0; j < 16; j++) {
    long i = 2L * (threadIdx.x + 256L * j);
    unsigned short u = ((const unsigned short*)x)[i];
    int e = (u >> 7) & 0xff, mant = u & 0x7f;
    bool b = (e == 0xff) || (e >= 141) || (e <= 93 && !(e == 0 && mant == 0));
    mybad += b ? 1 : 0;
  }
  atomicAdd(&bad, mybad);
  __syncthreads();
  if (threadIdx.x == 0) *flag = (bad > 1024) ? 0 : 1;
}

// ------------------------------------------------------------------
// prep_all: merged prep. Grid (64,8,32):
//  z 0..28 : weight pre-transpose W[k][n]->WT[n][k] bf16 (Wo folds the
//            merged-k permutation).
//  z == 29 : conv_proj — 3 f-rows per block.
//  z == 30 : xcB bf16 convert + zero of dgk/dgq/Sv atomic region.
//  z == 31 : xtB bf16 convert.
// ------------------------------------------------------------------
__global__ __launch_bounds__(256)
void prep_all(const void* __restrict__ Wk, const void* __restrict__ Wv,
              const void* __restrict__ Wq, const void* __restrict__ Wo,
              const void* __restrict__ W1, const void* __restrict__ W2,
              const void* __restrict__ W3, const void* __restrict__ Wmu,
              const void* __restrict__ proj, const void* __restrict__ x_ctx,
              const void* __restrict__ x_tgt,
              bf16* __restrict__ WkT, bf16* __restrict__ WvT,
              bf16* __restrict__ WqT, bf16* __restrict__ WoT,
              bf16* __restrict__ W1T, bf16* __restrict__ W2T,
              bf16* __restrict__ W3T, bf16* __restrict__ WmuT,
              bf16* __restrict__ projB, bf16* __restrict__ xcB,
              bf16* __restrict__ xtB,
              float* __restrict__ zbase, const int* __restrict__ dtFlag)
{
  __shared__ float tile[32][33];
  const int fl = *dtFlag;
  const int kt = blockIdx.x, nt = blockIdx.y, z = blockIdx.z, t = threadIdx.x;

  if (z == 29) {              // conv_proj
    int b = nt * 64 + kt;
#pragma unroll
    for (int r = 0; r < 3; r++) {
      int f = b * 3 + r;
      if (f < FT32 * 32) {
        float v = (f < NBF) ? ldx(proj, (long)f * 256 + t, fl) : 0.f;
        projB[(long)f * 256 + t] = __float2bfloat16(v);
      }
    }
    return;
  }
  if (z == 30) {              // xcB convert + atomic-region zero
    int b = nt * 64 + kt;
#pragma unroll
    for (int j = 0; j < 8; j++) {
      long i = (long)b * 2048 + j * 256 + t;
      xcB[i] = __float2bfloat16(ldx(x_ctx, i, fl));
    }
    if (b < 320) zbase[b * 256 + t] = 0.f;
    return;
  }
  if (z == 31) {              // xtB convert
    int b = nt * 64 + kt;
#pragma unroll
    for (int j = 0; j < 8; j++) {
      long i = (long)b * 2048 + j * 256 + t;
      xtB[i] = __float2bfloat16(ldx(x_tgt, i, fl));
    }
    return;
  }

  const void* in; bf16* out; int K; int perm = 0; long off = 0;
  if (z < 8)        { in = Wk;  out = WkT;  K = 256; off = (long)z * 65536; }
  else if (z < 16)  { in = Wv;  out = WvT;  K = 256; off = (long)(z - 8) * 65536; }
  else if (z < 24)  { in = Wq;  out = WqT;  K = 256; off = (long)(z - 16) * 65536; }
  else if (z == 24) { in = Wo;  out = WoT;  K = 2048; perm = 1; }
  else if (z == 25) { in = W1;  out = W1T;  K = 256; }
  else if (z == 26) { in = W2;  out = W2T;  K = 256; }
  else if (z == 27) { in = W3;  out = W3T;  K = 256; }
  else              { in = Wmu; out = WmuT; K = 256; }
  if (K == 256 && kt >= 8) return;
  const int k0 = kt * 32, n0 = nt * 32;
  const int row = t >> 3, cb = (t & 7) * 4;
  {
    int kk = k0 + row;
    int krow = perm ? (((kk & 255) << 3) | (kk >> 8)) : kk;
#pragma unroll
    for (int j = 0; j < 4; j++)
      tile[row][cb + j] = ldx(in, off + (long)krow * 256 + n0 + cb + j, fl);
  }
  __syncthreads();
  us4 o;
#pragma unroll
  for (int j = 0; j < 4; j++) o[j] = f2bu(tile[cb + j][row]);
  *(us4*)(out + off + (long)(n0 + row) * K + k0 + cb) = o;
}

// ------------------------------------------------------------------
// Unified MFMA GEMM v2, 64x64 tile, K-step 64 (proven round 5).
// Runs at 5 blocks/CU for kproj/vproj -> TLP covers latency; unchanged.
// ------------------------------------------------------------------
__global__ __launch_bounds__(256)
void gemm_mfma(const bf16* __restrict__ A, const bf16* __restrict__ BT,
               const void* __restrict__ bias,
               void* __restrict__ C, int cMode, int epi, int cT,
               const int* __restrict__ dtFlag, float* __restrict__ diagOut,
               float* __restrict__ svOut,
               int M, int N, int K, long sA, int divA, long sB, int modB, long sBias)
{
  __shared__ alignas(16) bf16 As[2][64 * 64];
  __shared__ alignas(16) bf16 Bs[2][64 * 64];
  const int fl = *dtFlag;
  const int cB = (cMode == 2) ? fl : cMode;
  const int t = threadIdx.x;
  const int bz = blockIdx.z;
  const long aOff = (long)(bz / divA) * sA;
  const long bOff = (long)(bz % modB) * sB;
  const long biasOff = (long)(bz % modB) * sBias;
  const long cOff = (long)bz * (long)M * N;
  const int m0 = blockIdx.y * 64, n0 = blockIdx.x * 64;
  const int w = t >> 6, l = t & 63, quad = l >> 4, ln = l & 15;
  const bf16* Ab = A + aOff + (long)m0 * K;
  const bf16* Bb = BT + bOff + (long)n0 * K;
  const int srow = l >> 3;            // 0..7 within the wave's 8-row slab
  const int scc = (l & 7) ^ srow;     // XOR swizzle chunk (row&7 == srow)
  f32x4 acc[4] = {};

  auto stage = [&](int buf, int k0) {
#pragma unroll
    for (int j = 0; j < 2; j++) {
      const int rbase = 32 * j + 8 * w;         // rbase&7 == 0
      const int row = rbase + srow;
      async_copy16(Ab + (long)row * K + k0 + scc * 8, &As[buf][rbase * 64]);
      async_copy16(Bb + (long)row * K + k0 + scc * 8, &Bs[buf][rbase * 64]);
    }
  };

  stage(0, 0);
  __syncthreads();   // full drain: buffer 0 ready

  int cur = 0;
  for (int k0 = 0; k0 < K; k0 += 64) {
    if (k0 + 64 < K) stage(cur ^ 1, k0 + 64);
    const bf16* Ac = &As[cur][0];
    const bf16* Bc = &Bs[cur][0];
    const int arow = 16 * w + ln;
#pragma unroll
    for (int ks = 0; ks < 2; ks++) {
      short8 a = *(const short8*)(Ac + arow * 64 + (((ks * 4 + quad) ^ (arow & 7)) << 3));
#pragma unroll
      for (int i = 0; i < 4; i++) {
        const int brow = 16 * i + ln;
        short8 b = *(const short8*)(Bc + brow * 64 + (((ks * 4 + quad) ^ (brow & 7)) << 3));
        acc[i] = __builtin_amdgcn_mfma_f32_16x16x32_bf16(a, b, acc[i], 0, 0, 0);
      }
    }
    asm volatile("s_waitcnt vmcnt(0)" ::: "memory");
    __builtin_amdgcn_s_barrier();
    __builtin_amdgcn_sched_barrier(0);
    cur ^= 1;
  }

  float s2[4] = {0.f, 0.f, 0.f, 0.f};
  if (cT == 2) {
    const int mm = m0 + 16 * w + quad * 4;
    const int tile = mm >> 5, off = mm & 31;
#pragma unroll
    for (int i = 0; i < 4; i++) {
      int n = n0 + 16 * i + ln;
      us4 cv;
      float colsum = 0.f;
#pragma unroll
      for (int r = 0; r < 4; r++) {
        float c = acc[i][r];
        if (epi >= 1) c += ldx(bias, biasOff + n, fl);
        if (epi == 2) c = fmaxf(c, 0.f);
        colsum += c;
        cv[r] = f2bu(c);
      }
      *(us4*)((bf16*)C + cOff + ((long)tile * N + n) * 32 + off) = cv;
      if (svOut) {
        colsum += __shfl_xor(colsum, 16);
        colsum += __shfl_xor(colsum, 32);
        if (quad == 0) atomicAdd(&svOut[(long)bz * N + n], colsum);
      }
    }
  } else {
#pragma unroll
    for (int i = 0; i < 4; i++) {
#pragma unroll
      for (int r = 0; r < 4; r++) {
        int m = m0 + 16 * w + quad * 4 + r;
        int n = n0 + 16 * i + ln;
        float c = acc[i][r];
        if (epi >= 1) c += ldx(bias, biasOff + n, fl);
        if (epi == 2) c = fmaxf(c, 0.f);
        s2[r] += c * c;
        stx(C, cOff + (long)m * N + n, c, cB);
      }
    }
  }
  if (diagOut) {
#pragma unroll
    for (int r = 0; r < 4; r++) {
      float s = s2[r];
      s += __shfl_xor(s, 1); s += __shfl_xor(s, 2);
      s += __shfl_xor(s, 4); s += __shfl_xor(s, 8);
      if (ln == 0)
        atomicAdd(&diagOut[(long)bz * M + m0 + 16 * w + quad * 4 + r], DIAG_SC * s);
    }
  }
}

// ------------------------------------------------------------------
// BM=32 GEMM v3: triple-buffered, stage distance 2, counted vmcnt(3)
// (3 DMAs per stage: 1 A slab + 2 B slabs per wave), tail vmcnt(0).
// Optional label fold. Generic K (MLP/Wmu K=256; Wo K=2048). LDS 36KB.
// ------------------------------------------------------------------
__global__ __launch_bounds__(256)
void gemm_mfma32v2(const bf16* __restrict__ A, const bf16* __restrict__ BT,
                   const void* __restrict__ bias,
                   void* __restrict__ C, int cMode, int epi,
                   const int* __restrict__ dtFlag, int M, int N, int K,
                   const void* __restrict__ labp, const void* __restrict__ labW)
{
  __shared__ alignas(16) bf16 As[3][32 * 64];
  __shared__ alignas(16) bf16 Bs[3][64 * 64];
  const int fl = *dtFlag;
  const int cB = (cMode == 2) ? fl : cMode;
  const int t = threadIdx.x;
  const int m0 = blockIdx.y * 32, n0 = blockIdx.x * 64;
  const int w = t >> 6, l = t & 63, quad = l >> 4, ln = l & 15;
  const int mi = w & 1, nh = w >> 1;
  const bf16* Ab = A + (long)m0 * K;
  const bf16* Bb = BT + (long)n0 * K;
  const int srow = l >> 3;
  const int scc = (l & 7) ^ srow;
  const int niter = K >> 6;
  f32x4 acc[2] = {};

  auto stage = [&](int buf, int k0) {
    async_copy16(Ab + (long)(8 * w + srow) * K + k0 + scc * 8, &As[buf][(8 * w) * 64]);
#pragma unroll
    for (int j = 0; j < 2; j++) {
      const int rbase = 32 * j + 8 * w;
      async_copy16(Bb + (long)(rbase + srow) * K + k0 + scc * 8, &Bs[buf][rbase * 64]);
    }
  };

  stage(0, 0);
  if (niter > 1) stage(1, 64);
  __syncthreads();   // full drain: buffers 0,1 ready

  int cur = 0;
  for (int it = 0; it < niter; ++it) {
    if (it + 2 < niter) {
      int nb = cur + 2; if (nb >= 3) nb -= 3;
      stage(nb, (it + 2) * 64);
    }
    __builtin_amdgcn_sched_barrier(0);
    const bf16* Ac = &As[cur][0];
    const bf16* Bc = &Bs[cur][0];
    const int arow = 16 * mi + ln;
#pragma unroll
    for (int ks = 0; ks < 2; ks++) {
      short8 a = *(const short8*)(Ac + arow * 64 + (((ks * 4 + quad) ^ (arow & 7)) << 3));
#pragma unroll
      for (int i = 0; i < 2; i++) {
        const int brow = 16 * (2 * nh + i) + ln;
        short8 b = *(const short8*)(Bc + brow * 64 + (((ks * 4 + quad) ^ (brow & 7)) << 3));
        acc[i] = __builtin_amdgcn_mfma_f32_16x16x32_bf16(a, b, acc[i], 0, 0, 0);
      }
    }
    // counted wait: keep stage(it+2) in flight; tail iterations drain
    if (it + 2 < niter) {
      asm volatile("s_waitcnt vmcnt(3)" ::: "memory");
    } else {
      asm volatile("s_waitcnt vmcnt(0)" ::: "memory");
    }
    __builtin_amdgcn_s_barrier();
    __builtin_amdgcn_sched_barrier(0);
    cur = (cur == 2) ? 0 : cur + 1;
  }

#pragma unroll
  for (int i = 0; i < 2; i++) {
#pragma unroll
    for (int r = 0; r < 4; r++) {
      int m = m0 + 16 * mi + quad * 4 + r;
      int n = n0 + 16 * (2 * nh + i) + ln;
      float c = acc[i][r];
      if (epi >= 1) c += ldx(bias, n, fl);
      if (labp) {
#pragma unroll
        for (int j = 0; j < 3; j++)
          c += ldx(labp, (long)m * 3 + j, fl) * ldx(labW, (long)(256 + j) * 256 + n, fl);
      }
      if (epi == 2) c = fmaxf(c, 0.f);
      stx(C, (long)m * N + n, c, cB);
    }
  }
}

// ------------------------------------------------------------------
// Key-side fused v10 (proven 90.7us): v5 staging (kS[3], distance-2,
// one barrier/iter, counted vmcnt(4) with tail drain) + de-atomized
// csRp/ktotp partial-store epilogue.
// ------------------------------------------------------------------
__global__ __launch_bounds__(256)
void key_fused_mfma(const bf16* __restrict__ k, const bf16* __restrict__ vQ,
                    const bf16* __restrict__ projB, const float* __restrict__ diagk,
                    float* __restrict__ ksumE, bf16* __restrict__ ctxQ,
                    float* __restrict__ mpart, float* __restrict__ csRp,
                    float* __restrict__ ktotp)
{
  __shared__ alignas(16) bf16 kS[3][32 * 256];
  __shared__ alignas(16) bf16 pS[2][64 * 40];
  __shared__ float wredM[4];
  __shared__ float wredK[4];

  const int bz = blockIdx.x, ft = blockIdx.y, f0 = ft * 64;
  const int t = threadIdx.x;
  const int w = t >> 6, l = t & 63, quad = l >> 4, ln = l & 15;
  const int fmine = f0 + 16 * w + ln;
  const bool fv = fmine < NBF;

  const bf16* kb = k + (long)bz * NC * 256;
  const bf16* vqb = vQ + (long)bz * 16 * 256 * 32;
  const float* db = diagk + bz * NC;

  auto stage = [&](int buf, int n0) {
#pragma unroll
    for (int j = 0; j < 4; j++) {
      int row = w * 8 + j * 2 + (l >> 5);
      int cc = (l & 31) ^ ((2 * j + (l >> 5)) & 7);   // = (l&31) ^ (row&7)
      async_copy16(kb + (long)(n0 + row) * 256 + cc * 8,
                   &kS[buf][w * 2048 + j * 512]);
    }
  };
  stage(0, 0);
  stage(1, 32);

  short8 pf[8];
  {
    const bf16* prow = projB + (long)fmine * 256;
#pragma unroll
    for (int kc = 0; kc < 8; kc++)
      pf[kc] = *(const short8*)(prow + kc * 32 + quad * 8);
  }

  f32x4 acc[4][4] = {};
  float ksumP = 0.f, mP = -1e30f;

  __syncthreads();   // full drain once: kS[0], kS[1] + pf ready

  int cur = 0;       // buffer holding tile `it`
  for (int it = 0; it < 16; it++) {
    const int n0 = it * 32;
    short8 bfr[4];
#pragma unroll
    for (int ei = 0; ei < 4; ei++) {
      int e = 64 * w + 16 * ei + ln;
      bfr[ei] = *(const short8*)(vqb + ((long)it * 256 + e) * 32 + quad * 8);
    }
    f32x4 dv0 = *(const f32x4*)(db + n0 + quad * 4);
    f32x4 dv1 = *(const f32x4*)(db + n0 + 16 + quad * 4);
    __builtin_amdgcn_sched_barrier(0);
    if (it + 2 < 16) {
      int nb = cur + 2; if (nb >= 3) nb -= 3;
      stage(nb, n0 + 64);
    }
    __builtin_amdgcn_sched_barrier(0);

    const bf16* kcur = &kS[cur][0];
    f32x4 dd[2][2] = {};
    __builtin_amdgcn_s_setprio(1);
#pragma unroll
    for (int kc = 0; kc < 8; kc++) {
      const int hf = kc & 1;
#pragma unroll
      for (int mi = 0; mi < 2; mi++) {
        short8 a = *(const short8*)(kcur + (16 * mi + ln) * 256 +
                                    (((kc * 4 + quad) ^ (ln & 7)) << 3));
        dd[mi][hf] = __builtin_amdgcn_mfma_f32_16x16x32_bf16(a, pf[kc], dd[mi][hf], 0, 0, 0);
      }
    }
    __builtin_amdgcn_s_setprio(0);
    bf16* pcur = &pS[it & 1][0];
#pragma unroll
    for (int mi = 0; mi < 2; mi++) {
      us4 ev;
      f32x4 dvv = mi ? dv1 : dv0;
#pragma unroll
      for (int r = 0; r < 4; r++) {
        float sc = DN * (dd[mi][0][r] + dd[mi][1][r]);
        float E = fv ? __expf(fminf(sc - dvv[r], 80.f)) : 0.f;
        unsigned short u = f2bu(E);
        ksumP += bf2f(u);
        if (fv) mP = fmaxf(mP, sc);
        ev[r] = u;
      }
      *(us4*)(pcur + (16 * w + ln) * 40 + 16 * mi + quad * 4) = ev;
    }
    if (it + 2 < 16) {
      asm volatile("s_waitcnt vmcnt(4) lgkmcnt(0)" ::: "memory");
    } else {
      asm volatile("s_waitcnt vmcnt(0) lgkmcnt(0)" ::: "memory");
    }
    __builtin_amdgcn_s_barrier();
    __builtin_amdgcn_sched_barrier(0);

    __builtin_amdgcn_s_setprio(1);
#pragma unroll
    for (int fh = 0; fh < 4; fh++) {
      short8 a = *(const short8*)(pcur + (16 * fh + ln) * 40 + quad * 8);
#pragma unroll
      for (int ei = 0; ei < 4; ei++)
        acc[fh][ei] = __builtin_amdgcn_mfma_f32_16x16x32_bf16(a, bfr[ei], acc[fh][ei], 0, 0, 0);
    }
    __builtin_amdgcn_s_setprio(0);
    cur = (cur == 2) ? 0 : cur + 1;
  }
  __syncthreads();

#pragma unroll
  for (int fh = 0; fh < 4; fh++) {
    const int ft32 = 2 * ft + (fh >> 1);
    const int f32b = 16 * (fh & 1) + quad * 4;
#pragma unroll
    for (int ei = 0; ei < 4; ei++) {
      int e = 64 * w + 16 * ei + ln;
      us4 cv;
#pragma unroll
      for (int r = 0; r < 4; r++) cv[r] = f2bu(acc[fh][ei][r]);
      *(us4*)(&ctxQ[((long)(bz * FT32 + ft32) * 256 + e) * 32 + f32b]) = cv;
    }
  }

  // csRp partial: column sum over this block's 64 f-rows per e (plain store)
#pragma unroll
  for (int ei = 0; ei < 4; ei++) {
    float col = 0.f;
#pragma unroll
    for (int fh = 0; fh < 4; fh++)
#pragma unroll
      for (int r = 0; r < 4; r++) col += acc[fh][ei][r];
    col += __shfl_xor(col, 16);
    col += __shfl_xor(col, 32);
    if (quad == 0)
      csRp[((long)bz * 23 + ft) * 256 + 64 * w + 16 * ei + ln] = col;
  }

  float s = ksumP;
  s += __shfl_xor(s, 16); s += __shfl_xor(s, 32);
  if (quad == 0 && fv) ksumE[(long)bz * NBF + fmine] = s;
  float s2 = s;
  s2 += __shfl_xor(s2, 1); s2 += __shfl_xor(s2, 2);
  s2 += __shfl_xor(s2, 4); s2 += __shfl_xor(s2, 8);
  if (l == 0) wredK[w] = s2;

  float m = mP;
#pragma unroll
  for (int off = 1; off < 64; off <<= 1) m = fmaxf(m, __shfl_xor(m, off));
  if (l == 0) wredM[w] = m;
  __syncthreads();
  if (t == 0) {
    mpart[bz * 23 + ft] = fmaxf(fmaxf(wredM[0], wredM[1]), fmaxf(wredM[2], wredM[3]));
    ktotp[bz * 23 + ft] = wredK[0] + wredK[1] + wredK[2] + wredK[3];
  }
}

// ------------------------------------------------------------------
// Query-side fused v10 (proven): q-proj prologue + folded finalize
// (csRp/ktotp/mpart partial reductions) + folded normalize.
// ------------------------------------------------------------------
__global__ __launch_bounds__(256)
void q_fused_mfma(const bf16* __restrict__ xtB, const bf16* __restrict__ WqT,
                  const void* __restrict__ bq, const bf16* __restrict__ projB,
                  const bf16* __restrict__ ctxQ,
                  const float* __restrict__ ksum, const float* __restrict__ Sv,
                  const float* __restrict__ csRp, const float* __restrict__ ktotp,
                  const float* __restrict__ mpart, const int* __restrict__ dtFlag,
                  bf16* __restrict__ merged)
{
  __shared__ alignas(16) bf16 projS[3][32 * 256];
  __shared__ alignas(16) bf16 eS[2][64 * 40];
  __shared__ float dS[64];
  __shared__ float svS[256];
  __shared__ float crS[256];
  __shared__ float sS[64];
  __shared__ float mS[64];
  __shared__ float seS[64];

  const int fl = *dtFlag;
  const int bz = blockIdx.x, nt = blockIdx.y, t = threadIdx.x;
  const int w = t >> 6, l = t & 63, quad = l >> 4, ln = l & 15;
  const int tq = bz / H_, hh = bz % H_;
  const bf16* cqb = ctxQ + (long)bz * FT32 * 256 * 32;
  const int srow = l >> 3, scc = (l & 7) ^ srow;

  // folded finalize_red: csR/ktot/mk from partials
  float mkv = -1e30f, ktv = 0.f;
  {
    float s = 0.f;
    for (int f2 = 0; f2 < 23; f2++) {
      s += csRp[((long)bz * 23 + f2) * 256 + t];
      mkv = fmaxf(mkv, mpart[bz * 23 + f2]);
      ktv += ktotp[bz * 23 + f2];
    }
    crS[t] = s;
  }
  const float emk = __expf(-mkv);
  const float ktotv = ktv;

  // ---- fused q-projection prologue (uses projS as scratch) ----
  bf16* scr = &projS[0][0];
  bf16* Asq = scr;             // [64][64] swizzled
  bf16* Bsq = scr + 4096;      // [256][64] swizzled
  const bf16* xq = xtB + ((long)tq * NT + nt * 64) * 256;
  const bf16* wq = WqT + (long)hh * 65536;
  f32x4 qacc[16] = {};

  for (int k0 = 0; k0 < 256; k0 += 64) {
#pragma unroll
    for (int j = 0; j < 2; j++) {
      const int rbase = 16 * w + 8 * j;
      async_copy16(xq + (long)(rbase + srow) * 256 + k0 + scc * 8, Asq + rbase * 64);
    }
#pragma unroll
    for (int j = 0; j < 8; j++) {
      const int rbase = 64 * w + 8 * j;
      async_copy16(wq + (long)(rbase + srow) * 256 + k0 + scc * 8, Bsq + rbase * 64);
    }
    asm volatile("s_waitcnt vmcnt(0)" ::: "memory");
    __builtin_amdgcn_s_barrier();
    __builtin_amdgcn_sched_barrier(0);
    const int arow = 16 * w + ln;
#pragma unroll
    for (int ks = 0; ks < 2; ks++) {
      short8 a = *(const short8*)(Asq + arow * 64 + (((ks * 4 + quad) ^ (arow & 7)) << 3));
#pragma unroll
      for (int g = 0; g < 16; g++) {
        const int brow = 16 * g + ln;
        short8 b = *(const short8*)(Bsq + brow * 64 + (((ks * 4 + quad) ^ (brow & 7)) << 3));
        qacc[g] = __builtin_amdgcn_mfma_f32_16x16x32_bf16(a, b, qacc[g], 0, 0, 0);
      }
    }
    __syncthreads();   // protect single-buffered restage / final scratch reuse
  }
  // bias + diag + bf16 q-tile into scr (stride 264)
  {
    float sum2[4] = {0.f, 0.f, 0.f, 0.f};
#pragma unroll
    for (int g = 0; g < 16; g++) {
      float bias = ldx(bq, (long)hh * 256 + 16 * g + ln, fl);
#pragma unroll
      for (int r = 0; r < 4; r++) {
        float v = qacc[g][r] + bias;
        sum2[r] += v * v;
        scr[(16 * w + quad * 4 + r) * 264 + 16 * g + ln] = __float2bfloat16(v);
      }
    }
#pragma unroll
    for (int r = 0; r < 4; r++) {
      float s = sum2[r];
      s += __shfl_xor(s, 1); s += __shfl_xor(s, 2);
      s += __shfl_xor(s, 4); s += __shfl_xor(s, 8);
      if (ln == 0) dS[16 * w + quad * 4 + r] = DIAG_SC * s;
    }
  }
  asm volatile("s_waitcnt lgkmcnt(0)" ::: "memory");
  __builtin_amdgcn_sched_barrier(0);
  // qf fragments (rows 16w+ln: written by THIS wave -> no barrier needed)
  short8 qf[8];
#pragma unroll
  for (int kc = 0; kc < 8; kc++)
    qf[kc] = *(const short8*)(scr + (16 * w + ln) * 264 + kc * 32 + quad * 8);
  __syncthreads();   // all reads done before stage_proj DMA overwrites scr

  auto stage_proj = [&](int buf, int f0n) {
#pragma unroll
    for (int j = 0; j < 4; j++) {
      int row = 8 * w + 2 * j + (l >> 5);
      int cc = (l & 31) ^ (row & 7);
      async_copy16(projB + (long)(f0n + row) * 256 + cc * 8,
                   &projS[buf][(8 * w + 2 * j) * 256]);
    }
  };
  stage_proj(0, 0);
  stage_proj(1, 32);
  svS[t] = Sv[bz * 256 + t];

  f32x4 acc[4][4] = {};           // [mh][ei]: rows 16mh+quad*4+r, e=16(4w+ei)+ln
  float sPart[4] = {0.f, 0.f, 0.f, 0.f};   // stR partial (rows 16w+quad*4+r)
  float sEp[4] = {0.f, 0.f, 0.f, 0.f};     // sE partial
  float mPart[4] = {0.f, 0.f, 0.f, 0.f};
  __syncthreads();   // full drain: projS[0..1] + LDS scalars ready

  int cur = 0;       // buffer holding tile `ft`
  for (int ft = 0; ft < FT32; ft++) {
    const int f0 = ft * 32;
    const bf16* pcur = &projS[cur][0];
    short8 cfr[4];
#pragma unroll
    for (int i = 0; i < 4; i++) {
      int e = 16 * (4 * w + i) + ln;
      cfr[i] = *(const short8*)(cqb + ((long)ft * 256 + e) * 32 + quad * 8);
    }
    const float kv0 = (f0 + ln < NBF) ? ksum[(long)bz * NBF + f0 + ln] : 0.f;
    const float kv1 = (f0 + 16 + ln < NBF) ? ksum[(long)bz * NBF + f0 + 16 + ln] : 0.f;
    __builtin_amdgcn_sched_barrier(0);
    if (ft + 2 < FT32) {
      int nb = cur + 2; if (nb >= 3) nb -= 3;
      stage_proj(nb, f0 + 64);
    }
    __builtin_amdgcn_sched_barrier(0);

    // Phase A: wave w owns rows 16w..16w+15, both f-halves
    f32x4 dd0 = {}, dd1 = {};
    __builtin_amdgcn_s_setprio(1);
#pragma unroll
    for (int kc = 0; kc < 8; kc++) {
      const int co = ((kc * 4 + quad) ^ (ln & 7)) << 3;
      short8 b0 = *(const short8*)(pcur + ln * 256 + co);
      dd0 = __builtin_amdgcn_mfma_f32_16x16x32_bf16(qf[kc], b0, dd0, 0, 0, 0);
      short8 b1 = *(const short8*)(pcur + (16 + ln) * 256 + co);
      dd1 = __builtin_amdgcn_mfma_f32_16x16x32_bf16(qf[kc], b1, dd1, 0, 0, 0);
    }
    __builtin_amdgcn_s_setprio(0);
    const bool fv0 = (f0 + ln) < NBF;
    const bool fv1 = (f0 + 16 + ln) < NBF;
    bf16* ecur = &eS[ft & 1][0];
#pragma unroll
    for (int r = 0; r < 4; r++) {
      float E0 = fv0 ? __expf(fminf(DN * dd0[r], 80.f)) : 0.f;
      float E1 = fv1 ? __expf(fminf(DN * dd1[r], 80.f)) : 0.f;
      bf16 h0 = __float2bfloat16(E0), h1v = __float2bfloat16(E1);
      float e0 = tofloat(h0), e1 = tofloat(h1v);
      ecur[(16 * w + quad * 4 + r) * 40 + ln] = h0;
      ecur[(16 * w + quad * 4 + r) * 40 + 16 + ln] = h1v;
      sPart[r] += e0 * kv0 + e1 * kv1;
      sEp[r] += e0 + e1;
      mPart[r] = fmaxf(mPart[r], fmaxf(e0, e1));
    }
    if (ft + 2 < FT32) {
      asm volatile("s_waitcnt vmcnt(4) lgkmcnt(0)" ::: "memory");
    } else {
      asm volatile("s_waitcnt vmcnt(0) lgkmcnt(0)" ::: "memory");
    }
    __builtin_amdgcn_s_barrier();
    __builtin_amdgcn_sched_barrier(0);

    // Phase B: all 4 m-halves, 4 e-tiles each (cfr reused)
    __builtin_amdgcn_s_setprio(1);
#pragma unroll
    for (int mh = 0; mh < 4; mh++) {
      short8 a = *(const short8*)(ecur + (16 * mh + ln) * 40 + quad * 8);
#pragma unroll
      for (int i = 0; i < 4; i++)
        acc[mh][i] = __builtin_amdgcn_mfma_f32_16x16x32_bf16(a, cfr[i], acc[mh][i], 0, 0, 0);
    }
    __builtin_amdgcn_s_setprio(0);
    cur = (cur == 2) ? 0 : cur + 1;
  }
  __syncthreads();

  // wave-private row stats: reduce over 16 lanes
#pragma unroll
  for (int r = 0; r < 4; r++) {
    float s = sPart[r], m = mPart[r], se = sEp[r];
#pragma unroll
    for (int off = 1; off < 16; off <<= 1) {
      s += __shfl_xor(s, off);
      m = fmaxf(m, __shfl_xor(m, off));
      se += __shfl_xor(se, off);
    }
    if (ln == 0) {
      sS[16 * w + quad * 4 + r] = s;
      mS[16 * w + quad * 4 + r] = m;
      seS[16 * w + quad * 4 + r] = se;
    }
  }
  __syncthreads();

#pragma unroll
  for (int mh = 0; mh < 4; mh++) {
#pragma unroll
    for (int r = 0; r < 4; r++) {
      int row = 16 * mh + quad * 4 + r;
      float st = sS[row];
      float se = seS[row];
      float mt = fmaxf(mS[row], 1e-30f);
      float c = __expf(-dS[row]) / mt;
      float A = c * se + (float)NBF * EPS_;
      float den = emk * (c * st + EPS_ * ktotv) + (float)NC * EPS_ * A;
      float inv = 1.f / den;
#pragma unroll
      for (int i = 0; i < 4; i++) {
        int e = 16 * (4 * w + i) + ln;
        float val = (emk * (c * acc[mh][i][r] + EPS_ * crS[e]) + EPS_ * svS[e] * A) * inv;
        merged[((long)tq * NT + nt * 64 + row) * 2048 + hh * 256 + e] =
            __float2bfloat16(val);
      }
    }
  }
}

// ------------------------------------------------------------------
extern "C" void kernel_launch(void* const* d_in, const int* in_sizes, int n_in,
                              void* d_out, int out_size, void* d_ws, size_t ws_size,
                              hipStream_t stream)
{
  const void* x_ctx = d_in[0];
  const void* label = d_in[1];
  const void* x_tgt = d_in[2];
  const void* W1 = d_in[3];
  const void* b1 = d_in[4];
  const void* W2 = d_in[5];
  const void* b2 = d_in[6];
  const void* W3 = d_in[7];
  const void* b3 = d_in[8];
  const void* Wk = d_in[9];
  const void* bk = d_in[10];
  const void* Wv = d_in[11];
  const void* bv = d_in[12];
  const void* Wq = d_in[13];
  const void* bq = d_in[14];
  const void* Wo = d_in[15];
  const void* bo = d_in[16];
  const void* Wmu = d_in[17];
  const void* bmu = d_in[18];
  const void* proj = d_in[19];

  // Arena (floats), peak ~93 MB. Overlays:
  //  xcB @ F2+1572864 (dead before ctxQ written by key_fused)
  //  rep @ F0+1048576 (written by Wo GEMM after q_fused; kB dead then)
  //  xtB: dedicated slot (written in prep, read in q_fused)
  float* W = (float*)d_ws;
  const long F0 = 0, F1 = 4194304, F2 = 8388608;
  const long CTXQ_F = (long)64 * FT32 * 256 * 32 / 2;
  const long F3 = F2 + CTXQ_F;
  bf16* kB = (bf16*)(W + F0);
  bf16* rep = (bf16*)(W + F0 + 1048576);
  bf16* vQ = (bf16*)(W + F1);
  bf16* merged = (bf16*)(W + F1);
  bf16* h1 = (bf16*)(W + F2);
  bf16* h2 = (bf16*)(W + F2 + 524288);
  bf16* cf = (bf16*)(W + F2 + 1048576);
  bf16* xcB = (bf16*)(W + F2 + 1572864);
  bf16* ctxQ = (bf16*)(W + F2);
  long o = F3;
  auto alloc = [&](long n) { float* p = W + o; o += n; return p; };
  float* zbase = W + o;
  float* dgk = alloc(32768);
  float* dgq = alloc(32768);            // kept for zero-region layout
  float* Sv = alloc(64 * 256);          // end of zeroed region (320 blocks)
  float* csR = alloc(64 * 256);         // unused (finalize folded)
  float* ktotR = alloc(64);             // unused
  alloc(192);
  float* ksumE = alloc((long)64 * NBF);
  float* mpart = alloc(64 * 23);
  float* mk = alloc(64);                // unused
  int* dtFlag = (int*)alloc(64);
  float* csRp = alloc((long)64 * 23 * 256);
  float* ktotp = alloc(64 * 23);
  bf16* projB = (bf16*)alloc((long)FT32 * 32 * 256 / 2);
  bf16* xtB = (bf16*)alloc(524288);   // 1M bf16 (8x512x256)
  bf16* WkT = (bf16*)alloc(262144);   // 8 x 256 x 256 bf16
  bf16* WvT = (bf16*)alloc(262144);
  bf16* WqT = (bf16*)alloc(262144);
  bf16* WoT = (bf16*)alloc(262144);   // 256 x 2048 bf16 (perm folded)
  bf16* W1T = (bf16*)alloc(32768);    // 256 x 256 bf16
  bf16* W2T = (bf16*)alloc(32768);
  bf16* W3T = (bf16*)alloc(32768);
  bf16* WmuT = (bf16*)alloc(32768);
  (void)ws_size; (void)in_sizes; (void)n_in; (void)out_size;
  (void)dgq; (void)csR; (void)ktotR; (void)mk;

  const dim3 B(256);
  detect_dtype<<<1, B, 0, stream>>>(x_ctx, dtFlag);
  // merged prep: weight transposes + conv_proj + xcB/xtB converts + zeroing
  prep_all<<<dim3(64, 8, 32), B, 0, stream>>>(
      Wk, Wv, Wq, Wo, W1, W2, W3, Wmu, proj, x_ctx, x_tgt,
      WkT, WvT, WqT, WoT, W1T, W2T, W3T, WmuT, projB, xcB, xtB, zbase, dtFlag);
  // 1. task-encoder MLP (BM=32 counted-wait gemm; layer 1 folds label+relu)
  gemm_mfma32v2<<<dim3(4, 128), B, 0, stream>>>(
      xcB, W1T, b1, h1, 1, 2, dtFlag, 4096, 256, 256, label, W1);
  gemm_mfma32v2<<<dim3(4, 128), B, 0, stream>>>(
      h1, W2T, b2, h2, 1, 2, dtFlag, 4096, 256, 256, nullptr, nullptr);
  gemm_mfma32v2<<<dim3(4, 128), B, 0, stream>>>(
      h2, W3T, b3, cf, 1, 2, dtFlag, 4096, 256, 256, nullptr, nullptr);
  // 2. k projection (fused diag), v projection (tiled -> vQ, fused Sv)
  gemm_mfma<<<dim3(4, 8, 64), B, 0, stream>>>(
      xcB, WkT, bk, kB, 1, 1, 0, dtFlag, dgk, nullptr,
      512, 256, 256, 131072L, 8, 65536L, 8, 256L);
  gemm_mfma<<<dim3(4, 8, 64), B, 0, stream>>>(
      cf, WvT, bv, vQ, 1, 1, 2, dtFlag, nullptr, Sv,
      512, 256, 256, 131072L, 8, 65536L, 8, 256L);
  // 3. key side (emits csRp / ktotp partials; finalize folded into q_fused)
  key_fused_mfma<<<dim3(64, 23), B, 0, stream>>>(kB, vQ, projB, dgk, ksumE, ctxQ,
                                                 mpart, csRp, ktotp);
  // 4. query side v10 (q-proj + finalize + normalize folded) -> merged
  q_fused_mfma<<<dim3(64, 8), B, 0, stream>>>(xtB, WqT, bq, projB, ctxQ, ksumE,
                                              Sv, csRp, ktotp, mpart, dtFlag, merged);
  // 5. Wo GEMM (single pass, K=2048, counted-wait) then Wmu
  gemm_mfma32v2<<<dim3(4, 128), B, 0, stream>>>(
      merged, WoT, bo, rep, 1, 1, dtFlag, 4096, 256, 2048, nullptr, nullptr);
  gemm_mfma32v2<<<dim3(4, 128), B, 0, stream>>>(
      rep, WmuT, bmu, d_out, 2, 1, dtFlag, 4096, 256, 256, nullptr, nullptr);
}